// Round 15
// baseline (269.648 us; speedup 1.0000x reference)
//
#include <hip/hip_runtime.h>
#include <hip/hip_bf16.h>

#define S_LEN 1024
#define HID 2048
#define NHEADS 16
#define KVHEADS 4
#define HD 128
#define KVW 512
#define FETCH_MAX 204
#define ALPHA_C 5.0f
#define SCALE_C 0.08838834764831845f

typedef __attribute__((ext_vector_type(8))) short bf16x8;
typedef __attribute__((ext_vector_type(4))) float f32x4;
typedef unsigned short ushort_t;

#define MFMA16(a, b, c) __builtin_amdgcn_mfma_f32_16x16x32_bf16(a, b, c, 0, 0, 0)

__device__ __forceinline__ ushort_t f2bf(float f) {
  unsigned u = __float_as_uint(f);
  return (ushort_t)((u + 0x7fffu + ((u >> 16) & 1u)) >> 16);
}
__device__ __forceinline__ float bf2f(ushort_t h) {
  return __uint_as_float(((unsigned)h) << 16);
}
// split 8 fp32 -> bf16 hi + lo
__device__ __forceinline__ void cvt8(float4 a, float4 b, bf16x8* vh, bf16x8* vl) {
  float e[8] = {a.x, a.y, a.z, a.w, b.x, b.y, b.z, b.w};
  bf16x8 h8, l8;
#pragma unroll
  for (int q = 0; q < 8; ++q) {
    ushort_t hh = f2bf(e[q]);
    h8[q] = (short)hh;
    l8[q] = (short)f2bf(e[q] - bf2f(hh));
  }
  *vh = h8;
  *vl = l8;
}

// async global->LDS, 16B per lane; dest = wave-uniform base + lane*16
__device__ __forceinline__ void gld16(const ushort_t* g, char* l) {
  __builtin_amdgcn_global_load_lds(
      (const __attribute__((address_space(1))) unsigned int*)g,
      (__attribute__((address_space(3))) unsigned int*)l, 16, 0, 0);
}

// ---------------- fp32 -> bf16, 8 elems/thread ------------------------------
__global__ __launch_bounds__(256) void to_bf16(const float* __restrict__ in,
                                               ushort_t* __restrict__ out, int n) {
  int i = (blockIdx.x * 256 + threadIdx.x) * 8;
  if (i >= n) return;
  float4 a = *(const float4*)(in + i);
  float4 b = *(const float4*)(in + i + 4);
  bf16x8 v;
  v[0] = (short)f2bf(a.x); v[1] = (short)f2bf(a.y);
  v[2] = (short)f2bf(a.z); v[3] = (short)f2bf(a.w);
  v[4] = (short)f2bf(b.x); v[5] = (short)f2bf(b.y);
  v[6] = (short)f2bf(b.z); v[7] = (short)f2bf(b.w);
  *(bf16x8*)(out + i) = v;
}

// ---------------- fp32 -> bf16 hi/lo split, 8 elems/thread ------------------
__global__ __launch_bounds__(256) void to_bf16_split(const float* __restrict__ in,
                                                     ushort_t* __restrict__ hi,
                                                     ushort_t* __restrict__ lo, int n) {
  int i = (blockIdx.x * 256 + threadIdx.x) * 8;
  if (i >= n) return;
  float4 a = *(const float4*)(in + i);
  float4 b = *(const float4*)(in + i + 4);
  bf16x8 vh, vl;
  cvt8(a, b, &vh, &vl);
  *(bf16x8*)(hi + i) = vh;
  *(bf16x8*)(lo + i) = vl;
}

// ============ ALL projections: fully async-staged, BM=32 for occupancy ======
// 1280 blocks x 256 thr. BM=32 BN=128 BK=64. B-panel-major + XCD swizzle.
// seg0: Qs 3-pass (512)  seg1: K 3-pass (128)  seg2: Q 1-pass (512)
// seg3: V 1-pass (128, no rope)
// 4 waves: wr=w&1 picks 16-row group; wc=w>>1 picks interleaved col frags
// nf = wc + 2i (RoPE pair (nf, nf+4) stays wave-local).
__global__ __launch_bounds__(256) void proj_all(
    const ushort_t* __restrict__ hhi, const ushort_t* __restrict__ hlo,
    const ushort_t* __restrict__ phi, const ushort_t* __restrict__ plo,
    const ushort_t* __restrict__ wqh, const ushort_t* __restrict__ wql,
    const ushort_t* __restrict__ wkh, const ushort_t* __restrict__ wkl,
    const ushort_t* __restrict__ wvb,
    ushort_t* __restrict__ oqs_h, ushort_t* __restrict__ oqs_l,
    ushort_t* __restrict__ ok_h, ushort_t* __restrict__ ok_l,
    ushort_t* __restrict__ oq, ushort_t* __restrict__ ov,
    const float* __restrict__ cosb, const float* __restrict__ sinb) {
  __shared__ char sm[40960];
  char* Ah = sm;            // 4KB  [32 rows][128B]
  char* Al = sm + 4096;     // 4KB
  char* Bh = sm + 8192;     // 16KB [128 rows][128B]
  char* Bl = sm + 24576;    // 16KB
  const int tid = threadIdx.x, w = tid >> 6, lane = tid & 63;
  const int lo = lane & 15, hi = lane >> 4;
  const int wr = w & 1, wc = w >> 1;
  const int bidr = blockIdx.x;
  const int bid = (bidr & 7) * 160 + (bidr >> 3);   // XCD-chunked: 1280=8*160

  int seg, idx;
  if (bid < 512)       { seg = 0; idx = bid; }
  else if (bid < 640)  { seg = 1; idx = bid - 512; }
  else if (bid < 1152) { seg = 2; idx = bid - 640; }
  else                 { seg = 3; idx = bid - 1152; }
  const int bm = (idx & 31) * 32, bn = (idx >> 5) * 128;   // B-panel-major
  const int N = (seg == 0 || seg == 2) ? HID : KVW;
  const bool three = (seg <= 1);
  const bool rope = (seg != 3);
  const ushort_t* A_h = (seg == 0) ? phi : hhi;
  const ushort_t* A_l = (seg == 0) ? plo : hlo;
  const ushort_t* W_h = (seg == 1) ? wkh : ((seg == 3) ? wvb : wqh);
  const ushort_t* W_l = (seg == 1) ? wkl : wql;

  // linear chunk i -> (row, col8) with inverse swizzle (bijective on 16B chunks)
  int Cr[4], Cc8[4];
#pragma unroll
  for (int p = 0; p < 4; ++p) {
    int i = p * 256 + tid;
    int r = i >> 3;
    Cr[p] = r;
    Cc8[p] = (((i << 4) & 127) ^ ((r & 7) << 4)) >> 4;
  }

  f32x4 acc[4];
#pragma unroll
  for (int i = 0; i < 4; ++i) acc[i] = f32x4{0.f, 0.f, 0.f, 0.f};

  for (int k0 = 0; k0 < HID; k0 += 64) {
    // A tile (4KB each h/l): 256 chunks, 1 per thread
    {
      size_t g = (size_t)(bm + Cr[0]) * HID + k0 + Cc8[0] * 8;
      gld16(A_h + g, Ah + tid * 16);
      if (three) gld16(A_l + g, Al + tid * 16);
    }
    // B tile (16KB each h/l): chunks p=0..3
#pragma unroll
    for (int p = 0; p < 4; ++p) {
      size_t g = (size_t)(bn + Cr[p]) * HID + k0 + Cc8[p] * 8;
      gld16(W_h + g, Bh + (p * 256 + w * 64) * 16);
      if (three) gld16(W_l + g, Bl + (p * 256 + w * 64) * 16);
    }
    __syncthreads();
#pragma unroll
    for (int ks = 0; ks < 2; ++ks) {
      const int ko = ks * 64 + hi * 16;
      bf16x8 ah, al;
      {
        int ar = wr * 16 + lo;
        int aoff = (ar * 128 + ko) ^ ((ar & 7) << 4);
        ah = *(const bf16x8*)(Ah + aoff);
        if (three) al = *(const bf16x8*)(Al + aoff);
      }
#pragma unroll
      for (int i = 0; i < 4; ++i) {
        int br = (wc + 2 * i) * 16 + lo;
        int boff = (br * 128 + ko) ^ ((br & 7) << 4);
        bf16x8 bh = *(const bf16x8*)(Bh + boff);
        if (three) {
          bf16x8 bl = *(const bf16x8*)(Bl + boff);
          acc[i] = MFMA16(ah, bh, acc[i]);
          acc[i] = MFMA16(ah, bl, acc[i]);
          acc[i] = MFMA16(al, bh, acc[i]);
        } else {
          acc[i] = MFMA16(ah, bh, acc[i]);
        }
      }
    }
    __syncthreads();
  }

  // epilogue: RoPE pairs (i, i+2): cols d and d+64 (head-local)
  ushort_t* Oh = (seg == 0) ? oqs_h : ok_h;
  ushort_t* Ol = (seg == 0) ? oqs_l : ok_l;
  ushort_t* O1 = (seg == 2) ? oq : ov;
#pragma unroll
  for (int i = 0; i < 2; ++i)
#pragma unroll
    for (int r = 0; r < 4; ++r) {
      int t = bm + wr * 16 + hi * 4 + r;
      int d = (wc + 2 * i) * 16 + lo;          // < 64
      float x1 = acc[i][r], x2 = acc[i + 2][r];
      float y1, y2;
      if (rope) {
        float c1 = cosb[t * HD + d], s1 = sinb[t * HD + d];
        float c2 = cosb[t * HD + d + 64], s2 = sinb[t * HD + d + 64];
        y1 = x1 * c1 - x2 * s1;
        y2 = x2 * c2 + x1 * s2;
      } else {
        y1 = x1; y2 = x2;
      }
      size_t o1 = (size_t)t * N + bn + d;
      size_t o2 = o1 + 64;
      if (three) {
        ushort_t h1 = f2bf(y1), h2 = f2bf(y2);
        Oh[o1] = h1; Ol[o1] = f2bf(y1 - bf2f(h1));
        Oh[o2] = h2; Ol[o2] = f2bf(y2 - bf2f(h2));
      } else {
        O1[o1] = f2bf(y1);
        O1[o2] = f2bf(y2);
      }
    }
}

// ---------------- 3-pass spec GEMM, causal tiles only, reg-prefetch ---------
__global__ __launch_bounds__(256) void spec3_gemm(
    const ushort_t* __restrict__ Qhi, const ushort_t* __restrict__ Qlo,
    const ushort_t* __restrict__ Khi, const ushort_t* __restrict__ Klo,
    float* __restrict__ spec) {
  __shared__ char sm[65536];
  char* Ah = sm;
  char* Al = sm + 16384;
  char* Bh = sm + 32768;
  char* Bl = sm + 49152;
  const int tid = threadIdx.x, w = tid >> 6, lane = tid & 63;
  const int lo = lane & 15, hi = lane >> 4;
  const int bidr = blockIdx.x;
  const int bid = (bidr & 7) * 72 + (bidr >> 3);   // XCD-chunked swizzle
  const int h = bid / 36;
  int tl = bid % 36;
  int mi = 0;
#pragma unroll
  for (int m = 1; m < 8; ++m) if ((m * (m + 1)) / 2 <= tl) mi = m;
  const int ni = tl - (mi * (mi + 1)) / 2;
  const int bm = mi * 128, bn = ni * 128;
  const ushort_t* Abh = Qhi + h * HD;
  const ushort_t* Abl = Qlo + h * HD;
  const ushort_t* Bbh = Khi + (h >> 2) * HD;
  const ushort_t* Bbl = Klo + (h >> 2) * HD;
  float* C = spec + (size_t)h * S_LEN * S_LEN;
  f32x4 acc[2][8];
#pragma unroll
  for (int m = 0; m < 2; ++m)
#pragma unroll
    for (int n = 0; n < 8; ++n) acc[m][n] = f32x4{0.f, 0.f, 0.f, 0.f};

  bf16x8 rAh[4], rAl[4], rBh[4], rBl[4];
#define LOAD_SPEC(K0)                                                         \
  {                                                                           \
    _Pragma("unroll")                                                         \
    for (int p = 0; p < 4; ++p) {                                             \
      int i2 = p * 256 + tid; int r = i2 >> 3, c = i2 & 7;                    \
      size_t ga = (size_t)(bm + r) * HID + (K0) + c * 8;                      \
      size_t gb = (size_t)(bn + r) * KVW + (K0) + c * 8;                      \
      rAh[p] = *(const bf16x8*)(Abh + ga);                                    \
      rAl[p] = *(const bf16x8*)(Abl + ga);                                    \
      rBh[p] = *(const bf16x8*)(Bbh + gb);                                    \
      rBl[p] = *(const bf16x8*)(Bbl + gb);                                    \
    }                                                                         \
  }

  LOAD_SPEC(0);
  for (int k0 = 0; k0 < HD; k0 += 64) {
#pragma unroll
    for (int p = 0; p < 4; ++p) {
      int i2 = p * 256 + tid; int r = i2 >> 3, c = i2 & 7;
      int off = (r * 128 + c * 16) ^ ((r & 7) << 4);
      *(bf16x8*)(Ah + off) = rAh[p];
      *(bf16x8*)(Al + off) = rAl[p];
      *(bf16x8*)(Bh + off) = rBh[p];
      *(bf16x8*)(Bl + off) = rBl[p];
    }
    __syncthreads();
    if (k0 + 64 < HD) LOAD_SPEC(k0 + 64);
#pragma unroll
    for (int ks = 0; ks < 2; ++ks) {
      const int ko = ks * 64 + hi * 16;
      bf16x8 ah[2], al[2];
#pragma unroll
      for (int m = 0; m < 2; ++m) {
        int r = w * 32 + m * 16 + lo;
        int off = (r * 128 + ko) ^ ((r & 7) << 4);
        ah[m] = *(const bf16x8*)(Ah + off);
        al[m] = *(const bf16x8*)(Al + off);
      }
#pragma unroll
      for (int n = 0; n < 8; ++n) {
        int r = n * 16 + lo;
        int off = (r * 128 + ko) ^ ((r & 7) << 4);
        bf16x8 bh = *(const bf16x8*)(Bh + off);
        bf16x8 bl = *(const bf16x8*)(Bl + off);
#pragma unroll
        for (int m = 0; m < 2; ++m) {
          acc[m][n] = MFMA16(ah[m], bh, acc[m][n]);
          acc[m][n] = MFMA16(ah[m], bl, acc[m][n]);
          acc[m][n] = MFMA16(al[m], bh, acc[m][n]);
        }
      }
    }
    __syncthreads();
  }
#undef LOAD_SPEC
#pragma unroll
  for (int m = 0; m < 2; ++m)
#pragma unroll
    for (int nf = 0; nf < 8; ++nf)
#pragma unroll
      for (int r = 0; r < 4; ++r) {
        int t = bm + w * 32 + m * 16 + hi * 4 + r;
        int j = bn + nf * 16 + lo;
        C[(size_t)t * S_LEN + j] = acc[m][nf][r] * SCALE_C;
      }
}

// ---------------- output GEMM: out = AO @ Wo^T, 2Mx2N waves, reg-prefetch ---
__global__ __launch_bounds__(256) void out_gemm(
    const ushort_t* __restrict__ A, const ushort_t* __restrict__ W,
    float* __restrict__ Out) {
  __shared__ char sm[24576];
  char* As = sm;            // 8KB
  char* Bs = sm + 8192;     // 16KB
  const int tid = threadIdx.x, w = tid >> 6, lane = tid & 63;
  const int lo = lane & 15, hi = lane >> 4;
  const int wm = w >> 1, wn = w & 1;
  const int bm = blockIdx.y * 64, bn = blockIdx.x * 128;
  f32x4 acc[2][4];
#pragma unroll
  for (int m = 0; m < 2; ++m)
#pragma unroll
    for (int i = 0; i < 4; ++i) acc[m][i] = f32x4{0.f, 0.f, 0.f, 0.f};

  bf16x8 rA[2], rB[4];
#define LOAD_OUT(K0)                                                          \
  {                                                                           \
    _Pragma("unroll")                                                         \
    for (int p = 0; p < 2; ++p) {                                             \
      int i2 = p * 256 + tid; int r = i2 >> 3, c = i2 & 7;                    \
      rA[p] = *(const bf16x8*)(A + (size_t)(bm + r) * HID + (K0) + c * 8);    \
    }                                                                         \
    _Pragma("unroll")                                                         \
    for (int p = 0; p < 4; ++p) {                                             \
      int i2 = p * 256 + tid; int r = i2 >> 3, c = i2 & 7;                    \
      rB[p] = *(const bf16x8*)(W + (size_t)(bn + r) * HID + (K0) + c * 8);    \
    }                                                                         \
  }

  LOAD_OUT(0);
  for (int k0 = 0; k0 < HID; k0 += 64) {
#pragma unroll
    for (int p = 0; p < 2; ++p) {
      int i2 = p * 256 + tid; int r = i2 >> 3, c = i2 & 7;
      *(bf16x8*)(As + ((r * 128 + c * 16) ^ ((r & 7) << 4))) = rA[p];
    }
#pragma unroll
    for (int p = 0; p < 4; ++p) {
      int i2 = p * 256 + tid; int r = i2 >> 3, c = i2 & 7;
      *(bf16x8*)(Bs + ((r * 128 + c * 16) ^ ((r & 7) << 4))) = rB[p];
    }
    __syncthreads();
    if (k0 + 64 < HID) LOAD_OUT(k0 + 64);
#pragma unroll
    for (int ks = 0; ks < 2; ++ks) {
      const int ko = ks * 64 + hi * 16;
      bf16x8 ah[2];
#pragma unroll
      for (int m = 0; m < 2; ++m) {
        int ar = wm * 32 + m * 16 + lo;
        ah[m] = *(const bf16x8*)(As + ((ar * 128 + ko) ^ ((ar & 7) << 4)));
      }
#pragma unroll
      for (int i = 0; i < 4; ++i) {
        int br = (wn + 2 * i) * 16 + lo;
        bf16x8 bf = *(const bf16x8*)(Bs + ((br * 128 + ko) ^ ((br & 7) << 4)));
#pragma unroll
        for (int m = 0; m < 2; ++m) acc[m][i] = MFMA16(ah[m], bf, acc[m][i]);
      }
    }
    __syncthreads();
  }
#undef LOAD_OUT
#pragma unroll
  for (int m = 0; m < 2; ++m)
#pragma unroll
    for (int i = 0; i < 4; ++i)
#pragma unroll
      for (int r = 0; r < 4; ++r) {
        int t = bm + wm * 32 + m * 16 + hi * 4 + r;
        Out[(size_t)t * HID + bn + (wn + 2 * i) * 16 + lo] = acc[m][i][r];
      }
}

// ---------------- per-(h,t>=204): rowmax + count(>= max-ALPHA), LDS-cached --
__global__ __launch_bounds__(256) void count_kernel(
    const float* __restrict__ spec, int* __restrict__ cnt) {
  const int t = blockIdx.x + FETCH_MAX, h = blockIdx.y, tid = threadIdx.x;
  const int w = tid >> 6, lane = tid & 63;
  __shared__ float rowc[1024];
  __shared__ float wmax[4];
  __shared__ int wcnt[4];
  const float* row = spec + ((size_t)h * S_LEN + t) * S_LEN;
  float mx = -1e30f;
  for (int j = tid; j <= t; j += 256) {
    float v = row[j];
    rowc[j] = v;
    mx = fmaxf(mx, v);
  }
#pragma unroll
  for (int d = 1; d < 64; d <<= 1) mx = fmaxf(mx, __shfl_xor(mx, d));
  if (lane == 0) wmax[w] = mx;
  __syncthreads();
  const float cut = fmaxf(fmaxf(wmax[0], wmax[1]), fmaxf(wmax[2], wmax[3])) - ALPHA_C;
  int c = 0;
  for (int j = tid; j <= t; j += 256) c += (rowc[j] >= cut) ? 1 : 0;
#pragma unroll
  for (int d = 1; d < 64; d <<= 1) c += __shfl_xor(c, d);
  if (lane == 0) wcnt[w] = c;
  __syncthreads();
  if (tid == 0) cnt[h * S_LEN + t] = wcnt[0] + wcnt[1] + wcnt[2] + wcnt[3];
}

// ---- wave-0 parallel bin select: largest bin b with suffix-count >= k ------
__device__ __forceinline__ void select_bin(const int* hist, int k, int w, int lane,
                                           int* sh_bin, int* sh_k) {
  if (w == 0) {
    const int base = 252 - 4 * lane;
    int c0 = hist[base], c1 = hist[base + 1], c2 = hist[base + 2], c3 = hist[base + 3];
    int s = c0 + c1 + c2 + c3;
    int p = s;
#pragma unroll
    for (int d = 1; d < 64; d <<= 1) {
      int q = __shfl_up(p, d);
      if (lane >= d) p += q;
    }
    unsigned long long m = __ballot(p >= k);
    int lsel = __ffsll((unsigned long long)m) - 1;
    if (lane == lsel) {
      int cum = p - s;
      int b;
      if (cum + c3 >= k) { b = base + 3; }
      else if (cum + c3 + c2 >= k) { cum += c3; b = base + 2; }
      else if (cum + c3 + c2 + c1 >= k) { cum += c3 + c2; b = base + 1; }
      else { cum += c3 + c2 + c1; b = base; }
      *sh_bin = b;
      *sh_k = k - cum;
    }
  }
}

// ---------------- exact k-th largest -> bitmask (fn computed inline) --------
__global__ __launch_bounds__(256) void thr_kernel(
    const float* __restrict__ spec, const int* __restrict__ cnt,
    unsigned long long* __restrict__ maskb) {
  const int t = blockIdx.x + FETCH_MAX, h = blockIdx.y;
  const int tid = threadIdx.x, w = tid >> 6, lane = tid & 63;
  __shared__ unsigned rowk[1024];
  __shared__ unsigned candA[1024];
  __shared__ unsigned candB[1024];
  __shared__ int hist4[4][256];
  __shared__ int hist[256];
  __shared__ int sh_bin, sh_k, sh_cnt;
  const float* row = spec + ((size_t)h * S_LEN + t) * S_LEN;
  const int n0 = t + 1;
  int s = 0;
#pragma unroll
  for (int hh = 0; hh < NHEADS; ++hh) s += cnt[hh * S_LEN + t];
  int k = s >> 4;
  if (k > FETCH_MAX) k = FETCH_MAX;
  hist4[0][tid] = 0; hist4[1][tid] = 0; hist4[2][tid] = 0; hist4[3][tid] = 0;
  if (tid == 0) sh_cnt = 0;
  __syncthreads();
  for (int j = tid; j < n0; j += 256) {
    unsigned bits = __float_as_uint(row[j]);
    unsigned u = (bits & 0x80000000u) ? ~bits : (bits | 0x80000000u);
    rowk[j] = u;
    atomicAdd(&hist4[w][u >> 24], 1);
  }
  __syncthreads();
  hist[tid] = hist4[0][tid] + hist4[1][tid] + hist4[2][tid] + hist4[3][tid];
  __syncthreads();
  select_bin(hist, k, w, lane, &sh_bin, &sh_k);
  __syncthreads();
  unsigned prefix = (unsigned)sh_bin << 24;
  k = sh_k;
  {
    const unsigned bsel = (unsigned)sh_bin;
    for (int j = tid; j < n0; j += 256) {
      unsigned u = rowk[j];
      if ((u >> 24) == bsel) candA[atomicAdd(&sh_cnt, 1)] = u;
    }
  }
  __syncthreads();
  int n = sh_cnt;
  unsigned* src = candA;
  unsigned* dst = candB;
#pragma unroll
  for (int rd = 0; rd < 3; ++rd) {
    const int shift = 16 - rd * 8;
    hist[tid] = 0;
    __syncthreads();
    for (int j = tid; j < n; j += 256) atomicAdd(&hist[(src[j] >> shift) & 255u], 1);
    __syncthreads();
    select_bin(hist, k, w, lane, &sh_bin, &sh_k);
    if (tid == 1) sh_cnt = 0;
    __syncthreads();
    const unsigned bsel = (unsigned)sh_bin;
    prefix |= bsel << shift;
    k = sh_k;
    if (shift > 0) {
      for (int j = tid; j < n; j += 256) {
        unsigned u = src[j];
        if (((u >> shift) & 255u) == bsel) dst[atomicAdd(&sh_cnt, 1)] = u;
      }
      __syncthreads();
      n = sh_cnt;
      unsigned* tmp = src; src = dst; dst = tmp;
    }
  }
  const unsigned kth = prefix;
#pragma unroll
  for (int s4 = 0; s4 < 4; ++s4) {
    int j = s4 * 256 + w * 64 + lane;
    bool bit = (j < n0) && (rowk[j] >= kth);
    unsigned long long m = __ballot(bit);
    if (lane == 0) maskb[((size_t)h * S_LEN + t) * 16 + (s4 * 4 + w)] = m;
  }
}

// ---------------- flash-style MFMA attention with bitmask (64-row blocks) ---
__global__ __launch_bounds__(256) void attn_mfma(
    const ushort_t* __restrict__ Qbf, const ushort_t* __restrict__ Kbf,
    const ushort_t* __restrict__ Vbf, const unsigned long long* __restrict__ maskb,
    ushort_t* __restrict__ AO) {
  __shared__ char sm[41984];
  const int tid = threadIdx.x, w = tid >> 6, lane = tid & 63;
  const int lo = lane & 15, hi = lane >> 4;
  const int bidr = blockIdx.x;
  const int bid = (bidr & 7) * 32 + (bidr >> 3);   // bijective: 256 = 8*32
  const int rt = bid & 15, h = bid >> 4;
  const int kvh = h >> 2;
  const int qrow = rt * 64 + w * 16 + lo;
  const int t0 = rt * 64 + w * 16 + hi * 4;

  bf16x8 qf[4];
  const ushort_t* qp = Qbf + (size_t)qrow * HID + h * HD;
#pragma unroll
  for (int ks = 0; ks < 4; ++ks) qf[ks] = *(const bf16x8*)(qp + ks * 32 + hi * 8);

  float mrun[4], lrun[4];
  f32x4 o[8];
#pragma unroll
  for (int r = 0; r < 4; ++r) { mrun[r] = -1e30f; lrun[r] = 0.f; }
#pragma unroll
  for (int n = 0; n < 8; ++n) o[n] = f32x4{0.f, 0.f, 0.f, 0.f};

  const int ntiles = rt + 1;
  for (int jt = 0; jt < ntiles; ++jt) {
    const int j0 = jt * 64;
#pragma unroll
    for (int p = 0; p < 4; ++p) {
      int idx = p * 256 + tid;
      int r = idx >> 4, c = idx & 15;
      bf16x8 v = *(const bf16x8*)(Kbf + (size_t)(j0 + r) * KVW + kvh * HD + c * 8);
      *(bf16x8*)(sm + ((r * 256 + c * 16) ^ ((r & 7) << 4))) = v;
    }
#pragma unroll
    for (int p = 0; p < 4; ++p) {
      int idx = p * 256 + tid;
      int j = idx & 63, dc = idx >> 6;
      bf16x8 v = *(const bf16x8*)(Vbf + (size_t)(j0 + j) * KVW + kvh * HD + dc * 8);
#pragma unroll
      for (int i = 0; i < 8; ++i) {
        int d = dc * 8 + i;
        *(ushort_t*)(sm + 16384 + ((d * 128 + j * 2) ^ ((d & 7) << 4))) = (ushort_t)v[i];
      }
    }
    __syncthreads();
    f32x4 s[4];
#pragma unroll
    for (int nf = 0; nf < 4; ++nf) {
      f32x4 a = f32x4{0.f, 0.f, 0.f, 0.f};
#pragma unroll
      for (int ks = 0; ks < 4; ++ks) {
        int r = nf * 16 + lo;
        bf16x8 kfr = *(const bf16x8*)(sm + ((r * 256 + ks * 64 + hi * 16) ^ ((r & 7) << 4)));
        a = MFMA16(qf[ks], kfr, a);
      }
      s[nf] = a;
    }
    unsigned long long wbits[4];
#pragma unroll
    for (int r = 0; r < 4; ++r) {
      int t = t0 + r;
      wbits[r] = (t >= FETCH_MAX) ? maskb[((size_t)h * S_LEN + t) * 16 + jt] : ~0ull;
    }
    float pvv[4][4];
    float tmax[4] = {-1e30f, -1e30f, -1e30f, -1e30f};
#pragma unroll
    for (int nf = 0; nf < 4; ++nf) {
      int j = j0 + nf * 16 + lo;
#pragma unroll
      for (int r = 0; r < 4; ++r) {
        int t = t0 + r;
        bool ok = (j <= t) && ((wbits[r] >> (nf * 16 + lo)) & 1ull);
        float val = ok ? s[nf][r] * SCALE_C : -1e30f;
        pvv[nf][r] = val;
        tmax[r] = fmaxf(tmax[r], val);
      }
    }
#pragma unroll
    for (int r = 0; r < 4; ++r) {
      float m = tmax[r];
      m = fmaxf(m, __shfl_xor(m, 1));
      m = fmaxf(m, __shfl_xor(m, 2));
      m = fmaxf(m, __shfl_xor(m, 4));
      m = fmaxf(m, __shfl_xor(m, 8));
      tmax[r] = m;
    }
    float alpha[4];
#pragma unroll
    for (int r = 0; r < 4; ++r) {
      float mnew = fmaxf(mrun[r], tmax[r]);
      alpha[r] = __expf(mrun[r] - mnew);
      mrun[r] = mnew;
    }
    float lsum[4] = {0.f, 0.f, 0.f, 0.f};
#pragma unroll
    for (int nf = 0; nf < 4; ++nf)
#pragma unroll
      for (int r = 0; r < 4; ++r) {
        float v2 = pvv[nf][r];
        float p = (v2 > -1e29f) ? __expf(v2 - mrun[r]) : 0.f;
        pvv[nf][r] = p;
        lsum[r] += p;
      }
#pragma unroll
    for (int r = 0; r < 4; ++r) {
      float ls = lsum[r];
      ls += __shfl_xor(ls, 1);
      ls += __shfl_xor(ls, 2);
      ls += __shfl_xor(ls, 4);
      ls += __shfl_xor(ls, 8);
      lrun[r] = lrun[r] * alpha[r] + ls;
#pragma unroll
      for (int n = 0; n < 8; ++n) o[n][r] *= alpha[r];
    }
    char* pb = sm + 32768 + w * 2304;
#pragma unroll
    for (int nf = 0; nf < 4; ++nf)
#pragma unroll
      for (int r = 0; r < 4; ++r)
        *(ushort_t*)(pb + (hi * 4 + r) * 144 + (nf * 16 + lo) * 2) = f2bf(pvv[nf][r]);
#pragma unroll
    for (int ks = 0; ks < 2; ++ks) {
      bf16x8 pa = *(const bf16x8*)(pb + lo * 144 + ks * 64 + hi * 16);
#pragma unroll
      for (int df = 0; df < 8; ++df) {
        int d = df * 16 + lo;
        bf16x8 vb = *(const bf16x8*)(sm + 16384 + ((d * 128 + ks * 64 + hi * 16) ^ ((d & 7) << 4)));
        o[df] = MFMA16(pa, vb, o[df]);
      }
    }
    __syncthreads();
  }
#pragma unroll
  for (int r = 0; r < 4; ++r) {
    float inv = 1.0f / lrun[r];
    int t = t0 + r;
#pragma unroll
    for (int df = 0; df < 8; ++df)
      AO[(size_t)t * HID + h * HD + df * 16 + lo] = f2bf(o[df][r] * inv);
  }
}

extern "C" void kernel_launch(void* const* d_in, const int* in_sizes, int n_in,
                              void* d_out, int out_size, void* d_ws, size_t ws_size,
                              hipStream_t stream) {
  const float* hidden = (const float*)d_in[0];
  const float* prev   = (const float*)d_in[1];
  const float* cosb   = (const float*)d_in[2];
  const float* sinb   = (const float*)d_in[3];
  const float* Wq     = (const float*)d_in[4];
  const float* Wk     = (const float*)d_in[5];
  const float* Wv     = (const float*)d_in[6];
  const float* Wo     = (const float*)d_in[7];
  float* out = (float*)d_out;

  char* ws = (char*)d_ws;
  const size_t MB = 1u << 20;
  float*    spec = (float*)(ws + 0);              // [0, 64MB)
  // conversion buffers inside spec region (all dead before spec3 writes)
  ushort_t* wqhi = (ushort_t*)(ws + 0);           // [0,8)
  ushort_t* wqlo = (ushort_t*)(ws + 8 * MB);      // [8,16)
  ushort_t* wkhi = (ushort_t*)(ws + 16 * MB);     // [16,18)
  ushort_t* wklo = (ushort_t*)(ws + 18 * MB);     // [18,20)
  ushort_t* wvbf = (ushort_t*)(ws + 20 * MB);     // [20,22)  2MB
  ushort_t* hhi  = (ushort_t*)(ws + 22 * MB);     // [22,26)
  ushort_t* hlo  = (ushort_t*)(ws + 26 * MB);     // [26,30)
  ushort_t* phi  = (ushort_t*)(ws + 30 * MB);     // [30,34)
  ushort_t* plo  = (ushort_t*)(ws + 34 * MB);     // [34,38)
  // persistent
  ushort_t* qshi = (ushort_t*)(ws + 64 * MB);     // 4MB (dead after spec3)
  ushort_t* qslo = (ushort_t*)(ws + 68 * MB);     // 4MB (dead after spec3)
  ushort_t* khi  = (ushort_t*)(ws + 72 * MB);     // 1MB
  ushort_t* klo  = (ushort_t*)(ws + 73 * MB);     // 1MB
  ushort_t* qbf  = (ushort_t*)(ws + 74 * MB);     // 4MB
  ushort_t* vbf  = (ushort_t*)(ws + 78 * MB);     // 1MB
  ushort_t* aobf = (ushort_t*)(ws + 79 * MB);     // 4MB
  unsigned long long* maskb = (unsigned long long*)(ws + 84 * MB);  // 2MB
  int*   cnt = (int*)(ws + 86 * MB);
  ushort_t* wobf = (ushort_t*)(ws + 64 * MB);     // 8MB, over qshi/qslo after spec3

  // conversions (weights + activations, once)
  to_bf16_split<<<2048, 256, 0, stream>>>(Wq, wqhi, wqlo, HID * HID);
  to_bf16_split<<<512, 256, 0, stream>>>(Wk, wkhi, wklo, KVW * HID);
  to_bf16<<<512, 256, 0, stream>>>(Wv, wvbf, KVW * HID);
  to_bf16_split<<<1024, 256, 0, stream>>>(hidden, hhi, hlo, S_LEN * HID);
  to_bf16_split<<<1024, 256, 0, stream>>>(prev, phi, plo, S_LEN * HID);

  // all projections (fully async staging, BM=32 for occupancy)
  proj_all<<<1280, 256, 0, stream>>>(hhi, hlo, phi, plo, wqhi, wqlo, wkhi,
                                     wklo, wvbf, qshi, qslo, khi, klo, qbf,
                                     vbf, cosb, sinb);

  // speculative scores (fp32-accurate, causal tiles only, reg-prefetch)
  spec3_gemm<<<576, 256, 0, stream>>>(qshi, qslo, khi, klo, spec);

  // mask statistics (exact on fp32 spec)
  count_kernel<<<dim3(S_LEN - FETCH_MAX, NHEADS), 256, 0, stream>>>(spec, cnt);
  thr_kernel<<<dim3(S_LEN - FETCH_MAX, NHEADS), 256, 0, stream>>>(spec, cnt, maskb);

  // Wo conversion into region freed after spec3
  to_bf16<<<2048, 256, 0, stream>>>(Wo, wobf, HID * HID);

  // attention (bitmask-driven, XCD-chunked)
  attn_mfma<<<256, 256, 0, stream>>>(qbf, khi, vbf, maskb, aobf);

  // output projection (reg-prefetch)
  out_gemm<<<dim3(16, 16), 256, 0, stream>>>(aobf, wobf, out);
}

// Round 16
// 239.418 us; speedup vs baseline: 1.1263x; 1.1263x over previous
//
#include <hip/hip_runtime.h>
#include <hip/hip_bf16.h>

#define S_LEN 1024
#define HID 2048
#define NHEADS 16
#define KVHEADS 4
#define HD 128
#define KVW 512
#define FETCH_MAX 204
#define ALPHA_C 5.0f
#define SCALE_C 0.08838834764831845f

typedef __attribute__((ext_vector_type(8))) short bf16x8;
typedef __attribute__((ext_vector_type(4))) float f32x4;
typedef unsigned short ushort_t;

#define MFMA16(a, b, c) __builtin_amdgcn_mfma_f32_16x16x32_bf16(a, b, c, 0, 0, 0)

__device__ __forceinline__ ushort_t f2bf(float f) {
  unsigned u = __float_as_uint(f);
  return (ushort_t)((u + 0x7fffu + ((u >> 16) & 1u)) >> 16);
}
__device__ __forceinline__ float bf2f(ushort_t h) {
  return __uint_as_float(((unsigned)h) << 16);
}
// split 8 fp32 -> bf16 hi + lo
__device__ __forceinline__ void cvt8(float4 a, float4 b, bf16x8* vh, bf16x8* vl) {
  float e[8] = {a.x, a.y, a.z, a.w, b.x, b.y, b.z, b.w};
  bf16x8 h8, l8;
#pragma unroll
  for (int q = 0; q < 8; ++q) {
    ushort_t hh = f2bf(e[q]);
    h8[q] = (short)hh;
    l8[q] = (short)f2bf(e[q] - bf2f(hh));
  }
  *vh = h8;
  *vl = l8;
}

// async global->LDS, 16B per lane; dest = wave-uniform base + lane*16
__device__ __forceinline__ void gld16(const ushort_t* g, char* l) {
  __builtin_amdgcn_global_load_lds(
      (const __attribute__((address_space(1))) unsigned int*)g,
      (__attribute__((address_space(3))) unsigned int*)l, 16, 0, 0);
}

// ---------------- fp32 -> bf16, 8 elems/thread ------------------------------
__global__ __launch_bounds__(256) void to_bf16(const float* __restrict__ in,
                                               ushort_t* __restrict__ out, int n) {
  int i = (blockIdx.x * 256 + threadIdx.x) * 8;
  if (i >= n) return;
  float4 a = *(const float4*)(in + i);
  float4 b = *(const float4*)(in + i + 4);
  bf16x8 v;
  v[0] = (short)f2bf(a.x); v[1] = (short)f2bf(a.y);
  v[2] = (short)f2bf(a.z); v[3] = (short)f2bf(a.w);
  v[4] = (short)f2bf(b.x); v[5] = (short)f2bf(b.y);
  v[6] = (short)f2bf(b.z); v[7] = (short)f2bf(b.w);
  *(bf16x8*)(out + i) = v;
}

// ---------------- fp32 -> bf16 hi/lo split, 8 elems/thread ------------------
__global__ __launch_bounds__(256) void to_bf16_split(const float* __restrict__ in,
                                                     ushort_t* __restrict__ hi,
                                                     ushort_t* __restrict__ lo, int n) {
  int i = (blockIdx.x * 256 + threadIdx.x) * 8;
  if (i >= n) return;
  float4 a = *(const float4*)(in + i);
  float4 b = *(const float4*)(in + i + 4);
  bf16x8 vh, vl;
  cvt8(a, b, &vh, &vl);
  *(bf16x8*)(hi + i) = vh;
  *(bf16x8*)(lo + i) = vl;
}

// ============ ALL projections: fp32 activations (reg+cvt), bf16 weights =====
// Weights staged ASYNC via global_load_lds (linear LDS dest, inverse-swizzled
// per-lane source so the swizzled ds_read side is unchanged).
// 640 blocks x 256 thr. BM=64 BN=128 BK=64. B-panel-major + XCD swizzle.
// seg0: Qs 3-pass (256)  seg1: K 3-pass (64)  seg2: Q 1-pass (256)
// seg3: V 1-pass (64, no rope)
__global__ __launch_bounds__(256) void proj_all(
    const float* __restrict__ hidden, const float* __restrict__ prev,
    const ushort_t* __restrict__ wqh, const ushort_t* __restrict__ wql,
    const ushort_t* __restrict__ wkh, const ushort_t* __restrict__ wkl,
    const ushort_t* __restrict__ wvb,
    ushort_t* __restrict__ oqs_h, ushort_t* __restrict__ oqs_l,
    ushort_t* __restrict__ ok_h, ushort_t* __restrict__ ok_l,
    ushort_t* __restrict__ oq, ushort_t* __restrict__ ov,
    const float* __restrict__ cosb, const float* __restrict__ sinb) {
  __shared__ char sm[49152];
  char* Ah = sm;            // 8KB
  char* Al = sm + 8192;     // 8KB
  char* Bh = sm + 16384;    // 16KB
  char* Bl = sm + 32768;    // 16KB
  const int tid = threadIdx.x, w = tid >> 6, lane = tid & 63;
  const int lo = lane & 15, hi = lane >> 4;
  const int wm = w >> 1, wn = w & 1;
  const int bidr = blockIdx.x;
  const int bid = (bidr & 7) * 80 + (bidr >> 3);   // XCD-chunked swizzle

  int seg, idx;
  if (bid < 256)      { seg = 0; idx = bid; }
  else if (bid < 320) { seg = 1; idx = bid - 256; }
  else if (bid < 576) { seg = 2; idx = bid - 320; }
  else                { seg = 3; idx = bid - 576; }
  const int bm = (idx & 15) * 64, bn = (idx >> 4) * 128;
  const int N = (seg == 0 || seg == 2) ? HID : KVW;
  const bool three = (seg <= 1);
  const bool rope = (seg != 3);
  const float* Afp = (seg == 0) ? prev : hidden;
  const ushort_t* W_h = (seg == 1) ? wkh : ((seg == 3) ? wvb : wqh);
  const ushort_t* W_l = (seg == 1) ? wkl : wql;

  // B-staging source decode: linear chunk i -> (row, col8) with inverse swizzle
  int Br[4], Bc8[4];
#pragma unroll
  for (int p = 0; p < 4; ++p) {
    int i = p * 256 + tid;
    int r = i >> 3;
    Br[p] = r;
    Bc8[p] = (((i << 4) & 127) ^ ((r & 7) << 4)) >> 4;
  }

  f32x4 acc[2][4];
#pragma unroll
  for (int m = 0; m < 2; ++m)
#pragma unroll
    for (int i = 0; i < 4; ++i) acc[m][i] = f32x4{0.f, 0.f, 0.f, 0.f};

  float4 rA[2][2];
#define LOAD_A(K0)                                                            \
  {                                                                           \
    _Pragma("unroll")                                                         \
    for (int p = 0; p < 2; ++p) {                                             \
      int i2 = p * 256 + tid; int r = i2 >> 3, c = i2 & 7;                    \
      size_t g = (size_t)(bm + r) * HID + (K0) + c * 8;                       \
      rA[p][0] = *(const float4*)(Afp + g);                                   \
      rA[p][1] = *(const float4*)(Afp + g + 4);                               \
    }                                                                         \
  }

  LOAD_A(0);
  for (int k0 = 0; k0 < HID; k0 += 64) {
    // B: async global->LDS (linear dest == swizzled content via source decode)
#pragma unroll
    for (int p = 0; p < 4; ++p) {
      const ushort_t* gh = W_h + (size_t)(bn + Br[p]) * HID + k0 + Bc8[p] * 8;
      gld16(gh, Bh + (p * 256 + w * 64) * 16);
      if (three) {
        const ushort_t* gl = W_l + (size_t)(bn + Br[p]) * HID + k0 + Bc8[p] * 8;
        gld16(gl, Bl + (p * 256 + w * 64) * 16);
      }
    }
    // A: convert + LDS write from staged regs
#pragma unroll
    for (int p = 0; p < 2; ++p) {
      int i2 = p * 256 + tid; int r = i2 >> 3, c = i2 & 7;
      int off = (r * 128 + c * 16) ^ ((r & 7) << 4);
      bf16x8 vh, vl;
      cvt8(rA[p][0], rA[p][1], &vh, &vl);
      *(bf16x8*)(Ah + off) = vh;
      if (three) *(bf16x8*)(Al + off) = vl;
    }
    __syncthreads();
    if (k0 + 64 < HID) LOAD_A(k0 + 64);
#pragma unroll
    for (int ks = 0; ks < 2; ++ks) {
      const int ko = ks * 64 + hi * 16;
      bf16x8 ah[2], al[2];
#pragma unroll
      for (int m = 0; m < 2; ++m) {
        int ar = wm * 32 + m * 16 + lo;
        int aoff = (ar * 128 + ko) ^ ((ar & 7) << 4);
        ah[m] = *(const bf16x8*)(Ah + aoff);
        if (three) al[m] = *(const bf16x8*)(Al + aoff);
      }
#pragma unroll
      for (int i = 0; i < 4; ++i) {
        int br = (wn + 2 * i) * 16 + lo;
        int boff = (br * 128 + ko) ^ ((br & 7) << 4);
        bf16x8 bh = *(const bf16x8*)(Bh + boff);
        if (three) {
          bf16x8 bl = *(const bf16x8*)(Bl + boff);
#pragma unroll
          for (int m = 0; m < 2; ++m) {
            acc[m][i] = MFMA16(ah[m], bh, acc[m][i]);
            acc[m][i] = MFMA16(ah[m], bl, acc[m][i]);
            acc[m][i] = MFMA16(al[m], bh, acc[m][i]);
          }
        } else {
#pragma unroll
          for (int m = 0; m < 2; ++m) acc[m][i] = MFMA16(ah[m], bh, acc[m][i]);
        }
      }
    }
    __syncthreads();
  }
#undef LOAD_A

  // epilogue: RoPE pairs (i, i+2): cols d and d+64 (head-local)
  ushort_t* Oh = (seg == 0) ? oqs_h : ok_h;
  ushort_t* Ol = (seg == 0) ? oqs_l : ok_l;
  ushort_t* O1 = (seg == 2) ? oq : ov;
#pragma unroll
  for (int m = 0; m < 2; ++m)
#pragma unroll
    for (int i = 0; i < 2; ++i)
#pragma unroll
      for (int r = 0; r < 4; ++r) {
        int t = bm + wm * 32 + m * 16 + hi * 4 + r;
        int d = (wn + 2 * i) * 16 + lo;          // < 64
        float x1 = acc[m][i][r], x2 = acc[m][i + 2][r];
        float y1, y2;
        if (rope) {
          float c1 = cosb[t * HD + d], s1 = sinb[t * HD + d];
          float c2 = cosb[t * HD + d + 64], s2 = sinb[t * HD + d + 64];
          y1 = x1 * c1 - x2 * s1;
          y2 = x2 * c2 + x1 * s2;
        } else {
          y1 = x1; y2 = x2;
        }
        size_t o1 = (size_t)t * N + bn + d;
        size_t o2 = o1 + 64;
        if (three) {
          ushort_t h1 = f2bf(y1), h2 = f2bf(y2);
          Oh[o1] = h1; Ol[o1] = f2bf(y1 - bf2f(h1));
          Oh[o2] = h2; Ol[o2] = f2bf(y2 - bf2f(h2));
        } else {
          O1[o1] = f2bf(y1);
          O1[o2] = f2bf(y2);
        }
      }
}

// ---------------- 3-pass spec GEMM, causal tiles only, reg-prefetch ---------
__global__ __launch_bounds__(256) void spec3_gemm(
    const ushort_t* __restrict__ Qhi, const ushort_t* __restrict__ Qlo,
    const ushort_t* __restrict__ Khi, const ushort_t* __restrict__ Klo,
    float* __restrict__ spec) {
  __shared__ char sm[65536];
  char* Ah = sm;
  char* Al = sm + 16384;
  char* Bh = sm + 32768;
  char* Bl = sm + 49152;
  const int tid = threadIdx.x, w = tid >> 6, lane = tid & 63;
  const int lo = lane & 15, hi = lane >> 4;
  const int bidr = blockIdx.x;
  const int bid = (bidr & 7) * 72 + (bidr >> 3);   // XCD-chunked swizzle
  const int h = bid / 36;
  int tl = bid % 36;
  int mi = 0;
#pragma unroll
  for (int m = 1; m < 8; ++m) if ((m * (m + 1)) / 2 <= tl) mi = m;
  const int ni = tl - (mi * (mi + 1)) / 2;
  const int bm = mi * 128, bn = ni * 128;
  const ushort_t* Abh = Qhi + h * HD;
  const ushort_t* Abl = Qlo + h * HD;
  const ushort_t* Bbh = Khi + (h >> 2) * HD;
  const ushort_t* Bbl = Klo + (h >> 2) * HD;
  float* C = spec + (size_t)h * S_LEN * S_LEN;
  f32x4 acc[2][8];
#pragma unroll
  for (int m = 0; m < 2; ++m)
#pragma unroll
    for (int n = 0; n < 8; ++n) acc[m][n] = f32x4{0.f, 0.f, 0.f, 0.f};

  bf16x8 rAh[4], rAl[4], rBh[4], rBl[4];
#define LOAD_SPEC(K0)                                                         \
  {                                                                           \
    _Pragma("unroll")                                                         \
    for (int p = 0; p < 4; ++p) {                                             \
      int i2 = p * 256 + tid; int r = i2 >> 3, c = i2 & 7;                    \
      size_t ga = (size_t)(bm + r) * HID + (K0) + c * 8;                      \
      size_t gb = (size_t)(bn + r) * KVW + (K0) + c * 8;                      \
      rAh[p] = *(const bf16x8*)(Abh + ga);                                    \
      rAl[p] = *(const bf16x8*)(Abl + ga);                                    \
      rBh[p] = *(const bf16x8*)(Bbh + gb);                                    \
      rBl[p] = *(const bf16x8*)(Bbl + gb);                                    \
    }                                                                         \
  }

  LOAD_SPEC(0);
  for (int k0 = 0; k0 < HD; k0 += 64) {
#pragma unroll
    for (int p = 0; p < 4; ++p) {
      int i2 = p * 256 + tid; int r = i2 >> 3, c = i2 & 7;
      int off = (r * 128 + c * 16) ^ ((r & 7) << 4);
      *(bf16x8*)(Ah + off) = rAh[p];
      *(bf16x8*)(Al + off) = rAl[p];
      *(bf16x8*)(Bh + off) = rBh[p];
      *(bf16x8*)(Bl + off) = rBl[p];
    }
    __syncthreads();
    if (k0 + 64 < HD) LOAD_SPEC(k0 + 64);
#pragma unroll
    for (int ks = 0; ks < 2; ++ks) {
      const int ko = ks * 64 + hi * 16;
      bf16x8 ah[2], al[2];
#pragma unroll
      for (int m = 0; m < 2; ++m) {
        int r = w * 32 + m * 16 + lo;
        int off = (r * 128 + ko) ^ ((r & 7) << 4);
        ah[m] = *(const bf16x8*)(Ah + off);
        al[m] = *(const bf16x8*)(Al + off);
      }
#pragma unroll
      for (int n = 0; n < 8; ++n) {
        int r = n * 16 + lo;
        int off = (r * 128 + ko) ^ ((r & 7) << 4);
        bf16x8 bh = *(const bf16x8*)(Bh + off);
        bf16x8 bl = *(const bf16x8*)(Bl + off);
#pragma unroll
        for (int m = 0; m < 2; ++m) {
          acc[m][n] = MFMA16(ah[m], bh, acc[m][n]);
          acc[m][n] = MFMA16(ah[m], bl, acc[m][n]);
          acc[m][n] = MFMA16(al[m], bh, acc[m][n]);
        }
      }
    }
    __syncthreads();
  }
#undef LOAD_SPEC
#pragma unroll
  for (int m = 0; m < 2; ++m)
#pragma unroll
    for (int nf = 0; nf < 8; ++nf)
#pragma unroll
      for (int r = 0; r < 4; ++r) {
        int t = bm + w * 32 + m * 16 + hi * 4 + r;
        int j = bn + nf * 16 + lo;
        C[(size_t)t * S_LEN + j] = acc[m][nf][r] * SCALE_C;
      }
}

// ---------------- output GEMM: out = AO @ Wo^T, 2Mx2N waves, reg-prefetch ---
__global__ __launch_bounds__(256) void out_gemm(
    const ushort_t* __restrict__ A, const ushort_t* __restrict__ W,
    float* __restrict__ Out) {
  __shared__ char sm[24576];
  char* As = sm;            // 8KB
  char* Bs = sm + 8192;     // 16KB
  const int tid = threadIdx.x, w = tid >> 6, lane = tid & 63;
  const int lo = lane & 15, hi = lane >> 4;
  const int wm = w >> 1, wn = w & 1;
  const int bm = blockIdx.y * 64, bn = blockIdx.x * 128;
  f32x4 acc[2][4];
#pragma unroll
  for (int m = 0; m < 2; ++m)
#pragma unroll
    for (int i = 0; i < 4; ++i) acc[m][i] = f32x4{0.f, 0.f, 0.f, 0.f};

  bf16x8 rA[2], rB[4];
#define LOAD_OUT(K0)                                                          \
  {                                                                           \
    _Pragma("unroll")                                                         \
    for (int p = 0; p < 2; ++p) {                                             \
      int i2 = p * 256 + tid; int r = i2 >> 3, c = i2 & 7;                    \
      rA[p] = *(const bf16x8*)(A + (size_t)(bm + r) * HID + (K0) + c * 8);    \
    }                                                                         \
    _Pragma("unroll")                                                         \
    for (int p = 0; p < 4; ++p) {                                             \
      int i2 = p * 256 + tid; int r = i2 >> 3, c = i2 & 7;                    \
      rB[p] = *(const bf16x8*)(W + (size_t)(bn + r) * HID + (K0) + c * 8);    \
    }                                                                         \
  }

  LOAD_OUT(0);
  for (int k0 = 0; k0 < HID; k0 += 64) {
#pragma unroll
    for (int p = 0; p < 2; ++p) {
      int i2 = p * 256 + tid; int r = i2 >> 3, c = i2 & 7;
      *(bf16x8*)(As + ((r * 128 + c * 16) ^ ((r & 7) << 4))) = rA[p];
    }
#pragma unroll
    for (int p = 0; p < 4; ++p) {
      int i2 = p * 256 + tid; int r = i2 >> 3, c = i2 & 7;
      *(bf16x8*)(Bs + ((r * 128 + c * 16) ^ ((r & 7) << 4))) = rB[p];
    }
    __syncthreads();
    if (k0 + 64 < HID) LOAD_OUT(k0 + 64);
#pragma unroll
    for (int ks = 0; ks < 2; ++ks) {
      const int ko = ks * 64 + hi * 16;
      bf16x8 ah[2];
#pragma unroll
      for (int m = 0; m < 2; ++m) {
        int ar = wm * 32 + m * 16 + lo;
        ah[m] = *(const bf16x8*)(As + ((ar * 128 + ko) ^ ((ar & 7) << 4)));
      }
#pragma unroll
      for (int i = 0; i < 4; ++i) {
        int br = (wn + 2 * i) * 16 + lo;
        bf16x8 bf = *(const bf16x8*)(Bs + ((br * 128 + ko) ^ ((br & 7) << 4)));
#pragma unroll
        for (int m = 0; m < 2; ++m) acc[m][i] = MFMA16(ah[m], bf, acc[m][i]);
      }
    }
    __syncthreads();
  }
#undef LOAD_OUT
#pragma unroll
  for (int m = 0; m < 2; ++m)
#pragma unroll
    for (int i = 0; i < 4; ++i)
#pragma unroll
      for (int r = 0; r < 4; ++r) {
        int t = bm + wm * 32 + m * 16 + hi * 4 + r;
        Out[(size_t)t * HID + bn + (wn + 2 * i) * 16 + lo] = acc[m][i][r];
      }
}

// ---------------- per-(h,t>=204): rowmax + count(>= max-ALPHA), LDS-cached --
__global__ __launch_bounds__(256) void count_kernel(
    const float* __restrict__ spec, int* __restrict__ cnt) {
  const int t = blockIdx.x + FETCH_MAX, h = blockIdx.y, tid = threadIdx.x;
  const int w = tid >> 6, lane = tid & 63;
  __shared__ float rowc[1024];
  __shared__ float wmax[4];
  __shared__ int wcnt[4];
  const float* row = spec + ((size_t)h * S_LEN + t) * S_LEN;
  float mx = -1e30f;
  for (int j = tid; j <= t; j += 256) {
    float v = row[j];
    rowc[j] = v;
    mx = fmaxf(mx, v);
  }
#pragma unroll
  for (int d = 1; d < 64; d <<= 1) mx = fmaxf(mx, __shfl_xor(mx, d));
  if (lane == 0) wmax[w] = mx;
  __syncthreads();
  const float cut = fmaxf(fmaxf(wmax[0], wmax[1]), fmaxf(wmax[2], wmax[3])) - ALPHA_C;
  int c = 0;
  for (int j = tid; j <= t; j += 256) c += (rowc[j] >= cut) ? 1 : 0;
#pragma unroll
  for (int d = 1; d < 64; d <<= 1) c += __shfl_xor(c, d);
  if (lane == 0) wcnt[w] = c;
  __syncthreads();
  if (tid == 0) cnt[h * S_LEN + t] = wcnt[0] + wcnt[1] + wcnt[2] + wcnt[3];
}

// ---- wave-0 parallel bin select: largest bin b with suffix-count >= k ------
__device__ __forceinline__ void select_bin(const int* hist, int k, int w, int lane,
                                           int* sh_bin, int* sh_k) {
  if (w == 0) {
    const int base = 252 - 4 * lane;
    int c0 = hist[base], c1 = hist[base + 1], c2 = hist[base + 2], c3 = hist[base + 3];
    int s = c0 + c1 + c2 + c3;
    int p = s;
#pragma unroll
    for (int d = 1; d < 64; d <<= 1) {
      int q = __shfl_up(p, d);
      if (lane >= d) p += q;
    }
    unsigned long long m = __ballot(p >= k);
    int lsel = __ffsll((unsigned long long)m) - 1;
    if (lane == lsel) {
      int cum = p - s;
      int b;
      if (cum + c3 >= k) { b = base + 3; }
      else if (cum + c3 + c2 >= k) { cum += c3; b = base + 2; }
      else if (cum + c3 + c2 + c1 >= k) { cum += c3 + c2; b = base + 1; }
      else { cum += c3 + c2 + c1; b = base; }
      *sh_bin = b;
      *sh_k = k - cum;
    }
  }
}

// ---------------- exact k-th largest -> bitmask (fn computed inline) --------
__global__ __launch_bounds__(256) void thr_kernel(
    const float* __restrict__ spec, const int* __restrict__ cnt,
    unsigned long long* __restrict__ maskb) {
  const int t = blockIdx.x + FETCH_MAX, h = blockIdx.y;
  const int tid = threadIdx.x, w = tid >> 6, lane = tid & 63;
  __shared__ unsigned rowk[1024];
  __shared__ unsigned candA[1024];
  __shared__ unsigned candB[1024];
  __shared__ int hist4[4][256];
  __shared__ int hist[256];
  __shared__ int sh_bin, sh_k, sh_cnt;
  const float* row = spec + ((size_t)h * S_LEN + t) * S_LEN;
  const int n0 = t + 1;
  // fn inline: min( floor(mean_h cnt), FETCH_MAX )
  int s = 0;
#pragma unroll
  for (int hh = 0; hh < NHEADS; ++hh) s += cnt[hh * S_LEN + t];
  int k = s >> 4;
  if (k > FETCH_MAX) k = FETCH_MAX;
  hist4[0][tid] = 0; hist4[1][tid] = 0; hist4[2][tid] = 0; hist4[3][tid] = 0;
  if (tid == 0) sh_cnt = 0;
  __syncthreads();
  for (int j = tid; j < n0; j += 256) {
    unsigned bits = __float_as_uint(row[j]);
    unsigned u = (bits & 0x80000000u) ? ~bits : (bits | 0x80000000u);
    rowk[j] = u;
    atomicAdd(&hist4[w][u >> 24], 1);
  }
  __syncthreads();
  hist[tid] = hist4[0][tid] + hist4[1][tid] + hist4[2][tid] + hist4[3][tid];
  __syncthreads();
  select_bin(hist, k, w, lane, &sh_bin, &sh_k);
  __syncthreads();
  unsigned prefix = (unsigned)sh_bin << 24;
  k = sh_k;
  {
    const unsigned bsel = (unsigned)sh_bin;
    for (int j = tid; j < n0; j += 256) {
      unsigned u = rowk[j];
      if ((u >> 24) == bsel) candA[atomicAdd(&sh_cnt, 1)] = u;
    }
  }
  __syncthreads();
  int n = sh_cnt;
  unsigned* src = candA;
  unsigned* dst = candB;
#pragma unroll
  for (int rd = 0; rd < 3; ++rd) {
    const int shift = 16 - rd * 8;
    hist[tid] = 0;
    __syncthreads();
    for (int j = tid; j < n; j += 256) atomicAdd(&hist[(src[j] >> shift) & 255u], 1);
    __syncthreads();
    select_bin(hist, k, w, lane, &sh_bin, &sh_k);
    if (tid == 1) sh_cnt = 0;
    __syncthreads();
    const unsigned bsel = (unsigned)sh_bin;
    prefix |= bsel << shift;
    k = sh_k;
    if (shift > 0) {
      for (int j = tid; j < n; j += 256) {
        unsigned u = src[j];
        if (((u >> shift) & 255u) == bsel) dst[atomicAdd(&sh_cnt, 1)] = u;
      }
      __syncthreads();
      n = sh_cnt;
      unsigned* tmp = src; src = dst; dst = tmp;
    }
  }
  const unsigned kth = prefix;
#pragma unroll
  for (int s4 = 0; s4 < 4; ++s4) {
    int j = s4 * 256 + w * 64 + lane;
    bool bit = (j < n0) && (rowk[j] >= kth);
    unsigned long long m = __ballot(bit);
    if (lane == 0) maskb[((size_t)h * S_LEN + t) * 16 + (s4 * 4 + w)] = m;
  }
}

// ---------------- flash-style MFMA attention with bitmask (64-row blocks) ---
// 1-D grid 256; XCD-chunked swizzle so each XCD owns 2 whole heads (K/V reuse)
__global__ __launch_bounds__(256) void attn_mfma(
    const ushort_t* __restrict__ Qbf, const ushort_t* __restrict__ Kbf,
    const ushort_t* __restrict__ Vbf, const unsigned long long* __restrict__ maskb,
    ushort_t* __restrict__ AO) {
  __shared__ char sm[41984];
  const int tid = threadIdx.x, w = tid >> 6, lane = tid & 63;
  const int lo = lane & 15, hi = lane >> 4;
  const int bidr = blockIdx.x;
  const int bid = (bidr & 7) * 32 + (bidr >> 3);   // bijective: 256 = 8*32
  const int rt = bid & 15, h = bid >> 4;
  const int kvh = h >> 2;
  const int qrow = rt * 64 + w * 16 + lo;
  const int t0 = rt * 64 + w * 16 + hi * 4;

  bf16x8 qf[4];
  const ushort_t* qp = Qbf + (size_t)qrow * HID + h * HD;
#pragma unroll
  for (int ks = 0; ks < 4; ++ks) qf[ks] = *(const bf16x8*)(qp + ks * 32 + hi * 8);

  float mrun[4], lrun[4];
  f32x4 o[8];
#pragma unroll
  for (int r = 0; r < 4; ++r) { mrun[r] = -1e30f; lrun[r] = 0.f; }
#pragma unroll
  for (int n = 0; n < 8; ++n) o[n] = f32x4{0.f, 0.f, 0.f, 0.f};

  const int ntiles = rt + 1;
  for (int jt = 0; jt < ntiles; ++jt) {
    const int j0 = jt * 64;
#pragma unroll
    for (int p = 0; p < 4; ++p) {
      int idx = p * 256 + tid;
      int r = idx >> 4, c = idx & 15;
      bf16x8 v = *(const bf16x8*)(Kbf + (size_t)(j0 + r) * KVW + kvh * HD + c * 8);
      *(bf16x8*)(sm + ((r * 256 + c * 16) ^ ((r & 7) << 4))) = v;
    }
#pragma unroll
    for (int p = 0; p < 4; ++p) {
      int idx = p * 256 + tid;
      int j = idx & 63, dc = idx >> 6;
      bf16x8 v = *(const bf16x8*)(Vbf + (size_t)(j0 + j) * KVW + kvh * HD + dc * 8);
#pragma unroll
      for (int i = 0; i < 8; ++i) {
        int d = dc * 8 + i;
        *(ushort_t*)(sm + 16384 + ((d * 128 + j * 2) ^ ((d & 7) << 4))) = (ushort_t)v[i];
      }
    }
    __syncthreads();
    f32x4 s[4];
#pragma unroll
    for (int nf = 0; nf < 4; ++nf) {
      f32x4 a = f32x4{0.f, 0.f, 0.f, 0.f};
#pragma unroll
      for (int ks = 0; ks < 4; ++ks) {
        int r = nf * 16 + lo;
        bf16x8 kfr = *(const bf16x8*)(sm + ((r * 256 + ks * 64 + hi * 16) ^ ((r & 7) << 4)));
        a = MFMA16(qf[ks], kfr, a);
      }
      s[nf] = a;
    }
    unsigned long long wbits[4];
#pragma unroll
    for (int r = 0; r < 4; ++r) {
      int t = t0 + r;
      wbits[r] = (t >= FETCH_MAX) ? maskb[((size_t)h * S_LEN + t) * 16 + jt] : ~0ull;
    }
    float pvv[4][4];
    float tmax[4] = {-1e30f, -1e30f, -1e30f, -1e30f};
#pragma unroll
    for (int nf = 0; nf < 4; ++nf) {
      int j = j0 + nf * 16 + lo;
#pragma unroll
      for (int r = 0; r < 4; ++r) {
        int t = t0 + r;
        bool ok = (j <= t) && ((wbits[r] >> (nf * 16 + lo)) & 1ull);
        float val = ok ? s[nf][r] * SCALE_C : -1e30f;
        pvv[nf][r] = val;
        tmax[r] = fmaxf(tmax[r], val);
      }
    }
#pragma unroll
    for (int r = 0; r < 4; ++r) {
      float m = tmax[r];
      m = fmaxf(m, __shfl_xor(m, 1));
      m = fmaxf(m, __shfl_xor(m, 2));
      m = fmaxf(m, __shfl_xor(m, 4));
      m = fmaxf(m, __shfl_xor(m, 8));
      tmax[r] = m;
    }
    float alpha[4];
#pragma unroll
    for (int r = 0; r < 4; ++r) {
      float mnew = fmaxf(mrun[r], tmax[r]);
      alpha[r] = __expf(mrun[r] - mnew);
      mrun[r] = mnew;
    }
    float lsum[4] = {0.f, 0.f, 0.f, 0.f};
#pragma unroll
    for (int nf = 0; nf < 4; ++nf)
#pragma unroll
      for (int r = 0; r < 4; ++r) {
        float v2 = pvv[nf][r];
        float p = (v2 > -1e29f) ? __expf(v2 - mrun[r]) : 0.f;
        pvv[nf][r] = p;
        lsum[r] += p;
      }
#pragma unroll
    for (int r = 0; r < 4; ++r) {
      float ls = lsum[r];
      ls += __shfl_xor(ls, 1);
      ls += __shfl_xor(ls, 2);
      ls += __shfl_xor(ls, 4);
      ls += __shfl_xor(ls, 8);
      lrun[r] = lrun[r] * alpha[r] + ls;
#pragma unroll
      for (int n = 0; n < 8; ++n) o[n][r] *= alpha[r];
    }
    char* pb = sm + 32768 + w * 2304;
#pragma unroll
    for (int nf = 0; nf < 4; ++nf)
#pragma unroll
      for (int r = 0; r < 4; ++r)
        *(ushort_t*)(pb + (hi * 4 + r) * 144 + (nf * 16 + lo) * 2) = f2bf(pvv[nf][r]);
#pragma unroll
    for (int ks = 0; ks < 2; ++ks) {
      bf16x8 pa = *(const bf16x8*)(pb + lo * 144 + ks * 64 + hi * 16);
#pragma unroll
      for (int df = 0; df < 8; ++df) {
        int d = df * 16 + lo;
        bf16x8 vb = *(const bf16x8*)(sm + 16384 + ((d * 128 + ks * 64 + hi * 16) ^ ((d & 7) << 4)));
        o[df] = MFMA16(pa, vb, o[df]);
      }
    }
    __syncthreads();
  }
#pragma unroll
  for (int r = 0; r < 4; ++r) {
    float inv = 1.0f / lrun[r];
    int t = t0 + r;
#pragma unroll
    for (int df = 0; df < 8; ++df)
      AO[(size_t)t * HID + h * HD + df * 16 + lo] = f2bf(o[df][r] * inv);
  }
}

extern "C" void kernel_launch(void* const* d_in, const int* in_sizes, int n_in,
                              void* d_out, int out_size, void* d_ws, size_t ws_size,
                              hipStream_t stream) {
  const float* hidden = (const float*)d_in[0];
  const float* prev   = (const float*)d_in[1];
  const float* cosb   = (const float*)d_in[2];
  const float* sinb   = (const float*)d_in[3];
  const float* Wq     = (const float*)d_in[4];
  const float* Wk     = (const float*)d_in[5];
  const float* Wv     = (const float*)d_in[6];
  const float* Wo     = (const float*)d_in[7];
  float* out = (float*)d_out;

  char* ws = (char*)d_ws;
  const size_t MB = 1u << 20;
  float*    spec = (float*)(ws + 0);              // [0, 64MB)
  // weight bf16 buffers inside spec region (dead before spec3 writes)
  ushort_t* wqhi = (ushort_t*)(ws + 0);           // 8MB
  ushort_t* wqlo = (ushort_t*)(ws + 8 * MB);      // 8MB
  ushort_t* wkhi = (ushort_t*)(ws + 16 * MB);     // 2MB
  ushort_t* wklo = (ushort_t*)(ws + 18 * MB);     // 2MB
  ushort_t* wvbf = (ushort_t*)(ws + 20 * MB);     // 2MB
  // persistent
  ushort_t* qshi = (ushort_t*)(ws + 64 * MB);     // 4MB (dead after spec3)
  ushort_t* qslo = (ushort_t*)(ws + 68 * MB);     // 4MB (dead after spec3)
  ushort_t* khi  = (ushort_t*)(ws + 72 * MB);     // 1MB
  ushort_t* klo  = (ushort_t*)(ws + 73 * MB);     // 1MB
  ushort_t* qbf  = (ushort_t*)(ws + 74 * MB);     // 4MB
  ushort_t* vbf  = (ushort_t*)(ws + 78 * MB);     // 1MB
  ushort_t* aobf = (ushort_t*)(ws + 79 * MB);     // 4MB
  unsigned long long* maskb = (unsigned long long*)(ws + 84 * MB);  // 2MB
  int*   cnt = (int*)(ws + 86 * MB);
  ushort_t* wobf = (ushort_t*)(ws + 64 * MB);     // 8MB, over qshi/qslo after spec3

  // weight conversions (once)
  to_bf16_split<<<2048, 256, 0, stream>>>(Wq, wqhi, wqlo, HID * HID);
  to_bf16_split<<<512, 256, 0, stream>>>(Wk, wkhi, wklo, KVW * HID);
  to_bf16<<<512, 256, 0, stream>>>(Wv, wvbf, KVW * HID);

  // all projections (fp32 activations reg-staged, bf16 weights async-staged)
  proj_all<<<640, 256, 0, stream>>>(hidden, prev, wqhi, wqlo, wkhi, wklo, wvbf,
                                    qshi, qslo, khi, klo, qbf, vbf, cosb, sinb);

  // speculative scores (fp32-accurate, causal tiles only)
  spec3_gemm<<<576, 256, 0, stream>>>(qshi, qslo, khi, klo, spec);

  // mask statistics (exact on fp32 spec)
  count_kernel<<<dim3(S_LEN - FETCH_MAX, NHEADS), 256, 0, stream>>>(spec, cnt);
  thr_kernel<<<dim3(S_LEN - FETCH_MAX, NHEADS), 256, 0, stream>>>(spec, cnt, maskb);

  // Wo conversion into region freed after spec3
  to_bf16<<<2048, 256, 0, stream>>>(Wo, wobf, HID * HID);

  // attention (bitmask-driven, XCD-chunked)
  attn_mfma<<<256, 256, 0, stream>>>(qbf, khi, vbf, maskb, aobf);

  // output projection (reg-prefetch)
  out_gemm<<<dim3(16, 16), 256, 0, stream>>>(aobf, wobf, out);
}